// Round 17
// baseline (529.114 us; speedup 1.0000x reference)
//
#include <hip/hip_runtime.h>
#include <hip/hip_bf16.h>

// ---------------------------------------------------------------------------
// KeypointWeighting R17: B fully register-resident in fp8 -> the K-loop has
// ZERO global B loads (probe_pf structure, measured at pf roofline 50us).
// 256 blocks (1/CU) x 768 thr (12 waves x 2 col-tiles): B = 80 VGPR/lane,
// loaded once. M-loop: 8 x 64-row tiles/block. A: f32 pf -> fp8 -> 3-slot
// LDS ring (verified swizzle scheme, 8B granules), pf pipe 4-deep, one
// lgkmcnt(0)+s_barrier per K-step, vmcnt never drained.
// Weights pre-scaled x64 in fp8 (avoids e4m3 subnormals); epilogue /64.
// fp32 fixup margin 0.08 covers fp8 logit error (~16 sigma).
// Pipeline: convert_w -> gemm -> scan -> scatter -> fill_tail.
// ---------------------------------------------------------------------------

typedef __attribute__((ext_vector_type(4))) float f32x4;

#define M_TOTAL 131072
#define C_DIM 640
#define H_DIM 256
#define O_DIM 128
#define KS 20
#define N_PTS 16384
#define NBLOCKS 256
#define NCHUNKS 2048
#define THRL -0.4054651081f   // log(0.4/0.6)
#define FIX_MARGIN 0.08f
#define INV64 0.015625f

#define OUT_COORD_OFF 16777216
#define OUT_MASK_OFF  17170432

// ws layout (bytes)
#define WT_OFF     0u          // fp8 weights x64: 245760 B
#define TMASK_OFF  262144u     // u64 [2048]
#define TAGG_OFF   278528u     // i32 [2048]
#define TEXCL_OFF  286720u     // i32 [2048]
#define COUNTS_OFF 294912u     // i32 [8]
#define G_OFF      1572864u    // f32 [131072][128]

#define LGKMCNT0 asm volatile("s_waitcnt lgkmcnt(0)" ::: "memory")
#define SBAR __builtin_amdgcn_s_barrier()

// K0: weights -> fp8 e4m3 (scaled x64), fragment-contiguous:
//   byte o = (((t*24 + ct)*16 + q)*4 + p)*8 + e  holds 64*W[k=t*32+p*8+e][n=ct*16+q]
// Each thread packs 4 bytes (one uint). 240 blocks x 256 = 61440 threads.
__global__ __launch_bounds__(256) void convert_w(const float* __restrict__ w1,
                                                 const float* __restrict__ wo,
                                                 unsigned int* __restrict__ Wu) {
  int i = blockIdx.x * 256 + threadIdx.x;
  if (i >= 61440) return;
  int g = i >> 1, h = i & 1;
  int p = g & 3, q = (g >> 2) & 15, tc = g >> 6;
  int ct = tc % 24, t = tc / 24;
  int n = ct * 16 + q;
  int kb = t * 32 + p * 8 + h * 4;
  float v[4];
#pragma unroll
  for (int e = 0; e < 4; ++e) {
    int k = kb + e;
    v[e] = ((n < H_DIM) ? w1[k * H_DIM + n] : wo[k * O_DIM + (n - H_DIM)]) * 64.f;
  }
  unsigned int u = __builtin_amdgcn_cvt_pk_fp8_f32(v[0], v[1], 0, false);
  u = __builtin_amdgcn_cvt_pk_fp8_f32(v[2], v[3], u, true);
  Wu[i] = u;
}

// K1: persistent-B fp8 GEMM + scores (+fp32 fixup) + chunk masks + G rows.
__global__ __launch_bounds__(768, 3) void gemm_fused(
    const float* __restrict__ pf, const unsigned char* __restrict__ Wf8,
    const float* __restrict__ w1, const float* __restrict__ b1,
    const float* __restrict__ w2, const float* __restrict__ b2,
    const float* __restrict__ bo, unsigned long long* __restrict__ tmask,
    int* __restrict__ tagg, float* __restrict__ G) {
  __shared__ __align__(16) unsigned char As[3][2048];  // 3 x 2 KB fp8 A ring
  __shared__ float lpart[8][64];
  __shared__ float llog[64];
  __shared__ float srow[64];
  __shared__ float fsum[4];
  __shared__ unsigned long long s_fm;

  const int tid = threadIdx.x;
  const int lane = tid & 63;
  const int wv = tid >> 6;        // 0..11
  const int q = lane & 15;
  const int p = lane >> 4;
  const int blk = blockIdx.x;

  // ---- B prologue: ALL weights into registers (2 col-tiles/wave, fp8)
  const char* bb = (const char*)Wf8 + (size_t)(q * 4 + p) * 8 + (size_t)(2 * wv) * 512;
  long B0[KS], B1[KS];
#pragma unroll
  for (int t = 0; t < KS; ++t) {
    B0[t] = *(const long*)(bb + (size_t)t * 12288);
    B1[t] = *(const long*)(bb + (size_t)t * 12288 + 512);
  }

  // A staging map (tid<512): row=tid>>3, kh=tid&7; 8B granule g=(kh>>1)*64+row,
  // phys = g ^ (g>>6); 4B write at +(kh&1)*4. Read: granule p*64+rt*16+q ^ p.
  const int row_s = tid >> 3;
  const int kh = tid & 7;
  const int wboff = ((((kh >> 1) << 6) + row_s) ^ (kh >> 1)) * 8 + (kh & 1) * 4;

#define STW(SLOT, F)                                                          \
  {                                                                           \
    unsigned int u_ = __builtin_amdgcn_cvt_pk_fp8_f32((F).x, (F).y, 0, false);\
    u_ = __builtin_amdgcn_cvt_pk_fp8_f32((F).z, (F).w, u_, true);             \
    *(unsigned int*)&As[SLOT][wboff] = u_;                                    \
  }

#pragma unroll 1
  for (int mt = 0; mt < 8; ++mt) {
    const int m0 = blk * 512 + mt * 64;
    const float* asrc = pf + (size_t)(m0 + row_s) * C_DIM + kh * 4;

    f32x4 acc[2][4];
#pragma unroll
    for (int i = 0; i < 2; ++i)
#pragma unroll
      for (int rt = 0; rt < 4; ++rt) acc[i][rt] = (f32x4){0.f, 0.f, 0.f, 0.f};

    float4 pipe[4];
    if (tid < 512) {
      pipe[0] = *(const float4*)(asrc);
      pipe[1] = *(const float4*)(asrc + 32);
      pipe[2] = *(const float4*)(asrc + 64);
      STW(0, pipe[0]);
    }
    LGKMCNT0;
    SBAR;

#pragma unroll
    for (int t = 0; t < KS; ++t) {
      if (tid < 512) {
        if (t + 3 < KS) pipe[(t + 3) & 3] = *(const float4*)(asrc + (t + 3) * 32);
        if (t + 1 < KS) STW((t + 1) % 3, pipe[(t + 1) & 3]);
      }
      LGKMCNT0;
      SBAR;
      long a0 = *(const long*)&As[t % 3][((p * 64 + 0 * 16 + q) ^ p) * 8];
      long a1 = *(const long*)&As[t % 3][((p * 64 + 1 * 16 + q) ^ p) * 8];
      long a2 = *(const long*)&As[t % 3][((p * 64 + 2 * 16 + q) ^ p) * 8];
      long a3 = *(const long*)&As[t % 3][((p * 64 + 3 * 16 + q) ^ p) * 8];
      acc[0][0] = __builtin_amdgcn_mfma_f32_16x16x32_fp8_fp8(a0, B0[t], acc[0][0], 0, 0, 0);
      acc[1][0] = __builtin_amdgcn_mfma_f32_16x16x32_fp8_fp8(a0, B1[t], acc[1][0], 0, 0, 0);
      acc[0][1] = __builtin_amdgcn_mfma_f32_16x16x32_fp8_fp8(a1, B0[t], acc[0][1], 0, 0, 0);
      acc[1][1] = __builtin_amdgcn_mfma_f32_16x16x32_fp8_fp8(a1, B1[t], acc[1][1], 0, 0, 0);
      acc[0][2] = __builtin_amdgcn_mfma_f32_16x16x32_fp8_fp8(a2, B0[t], acc[0][2], 0, 0, 0);
      acc[1][2] = __builtin_amdgcn_mfma_f32_16x16x32_fp8_fp8(a2, B1[t], acc[1][2], 0, 0, 0);
      acc[0][3] = __builtin_amdgcn_mfma_f32_16x16x32_fp8_fp8(a3, B0[t], acc[0][3], 0, 0, 0);
      acc[1][3] = __builtin_amdgcn_mfma_f32_16x16x32_fp8_fp8(a3, B1[t], acc[1][3], 0, 0, 0);
    }
    __syncthreads();

    // ---- epilogue for this 64-row tile ----
    // logit partials: waves 0..7 own w1 col-tiles ct=2wv,2wv+1 (cols 0..255)
    if (wv < 8) {
      float b1v[2], w2v[2];
#pragma unroll
      for (int i = 0; i < 2; ++i) {
        int col = (2 * wv + i) * 16 + q;
        b1v[i] = b1[col];
        w2v[i] = w2[col];
      }
#pragma unroll
      for (int rt = 0; rt < 4; ++rt) {
        float pr[4] = {0.f, 0.f, 0.f, 0.f};
#pragma unroll
        for (int i = 0; i < 2; ++i)
#pragma unroll
          for (int r = 0; r < 4; ++r)
            pr[r] += fmaxf(acc[i][rt][r] * INV64 + b1v[i], 0.f) * w2v[i];
#pragma unroll
        for (int mk = 1; mk < 16; mk <<= 1)
#pragma unroll
          for (int r = 0; r < 4; ++r) pr[r] += __shfl_xor(pr[r], mk);
        if (q == 0)
#pragma unroll
          for (int r = 0; r < 4; ++r) lpart[wv][rt * 16 + p * 4 + r] = pr[r];
      }
    }
    __syncthreads();

    bool nf = false;
    if (tid < 64) {
      float lg = b2[0];
#pragma unroll
      for (int w = 0; w < 8; ++w) lg += lpart[w][tid];
      llog[tid] = lg;
      nf = fabsf(lg - THRL) < FIX_MARGIN;
    }
    unsigned long long fm = __ballot(nf);
    if (tid == 0) s_fm = fm;
    __syncthreads();

    // exact fp32 recompute of borderline rows (~0.1/tile)
    unsigned long long fixmask = s_fm;
    while (fixmask) {
      int row = __ffsll(fixmask) - 1;
      fixmask &= fixmask - 1;
      if (tid < 256) {
        const float* prow = pf + (size_t)(m0 + row) * C_DIM;
        float a0 = 0.f, a1 = 0.f;
        for (int c = 0; c < C_DIM; c += 2) {
          a0 = fmaf(prow[c], w1[(size_t)c * H_DIM + tid], a0);
          a1 = fmaf(prow[c + 1], w1[(size_t)(c + 1) * H_DIM + tid], a1);
        }
        float v = fmaxf(a0 + a1 + b1[tid], 0.f) * w2[tid];
#pragma unroll
        for (int mk = 1; mk < 64; mk <<= 1) v += __shfl_xor(v, mk);
        if (lane == 0) fsum[tid >> 6] = v;
      }
      __syncthreads();
      if (tid == 0)
        llog[row] = fsum[0] + fsum[1] + fsum[2] + fsum[3] + b2[0];
      __syncthreads();
    }

    // selection mask + scores
    bool sel = false;
    if (tid < 64) {
      float flog = llog[tid];
      sel = flog > THRL;
      srow[tid] = 1.f / (1.f + expf(-flog));
    }
    unsigned long long mk2 = __ballot(sel);
    if (tid == 0) {
      int ch = blk * 8 + mt;
      tmask[ch] = mk2;
      tagg[ch] = __popcll(mk2);
    }
    __syncthreads();

    // G rows: waves 8..11 own wo col-tiles ct=16..23 -> gcol 0..127
    if (wv >= 8) {
#pragma unroll
      for (int i = 0; i < 2; ++i) {
        int gcol = ((wv - 8) * 2 + i) * 16 + q;
        float bov = bo[gcol];
#pragma unroll
        for (int rt = 0; rt < 4; ++rt)
#pragma unroll
          for (int r = 0; r < 4; ++r) {
            int row = rt * 16 + p * 4 + r;
            G[(size_t)(m0 + row) * O_DIM + gcol] =
                fmaf(acc[i][rt][r] * INV64, srow[row], bov);
          }
      }
    }
    __syncthreads();
  }
#undef STW
}

// K2: per-batch exclusive scan of 256 chunk aggregates. grid 8, block 256.
__global__ __launch_bounds__(256) void scan_tiles(const int* __restrict__ tagg,
                                                  int* __restrict__ texcl,
                                                  int* __restrict__ counts) {
  __shared__ int wsum[4];
  const int c = blockIdx.x, t = threadIdx.x;
  const int lane = t & 63, w = t >> 6;
  int v = tagg[c * 256 + t];
  int inc = v;
#pragma unroll
  for (int d = 1; d < 64; d <<= 1) {
    int n = __shfl_up(inc, d);
    if (lane >= d) inc += n;
  }
  if (lane == 63) wsum[w] = inc;
  __syncthreads();
  int base = 0;
#pragma unroll
  for (int ww = 0; ww < 4; ++ww)
    if (ww < w) base += wsum[ww];
  texcl[c * 256 + t] = base + inc - v;
  if (t == 255) counts[c] = base + inc;
}

// K3: compact selected rows per 64-row chunk. grid 2048, block 512.
__global__ __launch_bounds__(512) void scatter(
    const float* __restrict__ G, const unsigned long long* __restrict__ tmask,
    const int* __restrict__ texcl, const float* __restrict__ pc,
    float* __restrict__ out) {
  const int ch = blockIdx.x;
  const int tid = threadIdx.x;
  const int lane = tid & 63;
  const int wv = tid >> 6;
  const unsigned long long mask = tmask[ch];
  const int base = (ch >> 8) * N_PTS + texcl[ch];
  const int m0 = ch * 64;
#pragma unroll
  for (int j = 0; j < 8; ++j) {
    const int row = wv * 8 + j;
    if (!((mask >> row) & 1ull)) continue;
    const int dst = base + __popcll(mask & ((1ull << row) - 1ull));
    const int m = m0 + row;
    float2 g = *(const float2*)(G + (size_t)m * O_DIM + lane * 2);
    *(float2*)(out + (size_t)dst * O_DIM + lane * 2) = g;
    if (lane == 0) {
      float c0 = pc[m * 3], c1 = pc[m * 3 + 1], c2 = pc[m * 3 + 2];
      float* oc = out + OUT_COORD_OFF;
      oc[dst * 3] = c0; oc[dst * 3 + 1] = c1; oc[dst * 3 + 2] = c2;
      out[OUT_MASK_OFF + dst] = (c0 == 0.f || c1 == 0.f || c2 == 0.f) ? 1.f : 0.f;
    }
  }
}

// K4: zero-fill padding tail rows; mask=1 there. 2048 grid-stride blocks.
__global__ __launch_bounds__(256) void fill_tail(const int* __restrict__ counts,
                                                 float* __restrict__ out) {
  const int lane = threadIdx.x & 63;
  for (int m = blockIdx.x * 4 + (threadIdx.x >> 6); m < M_TOTAL; m += 8192) {
    int b = m >> 14, j = m & (N_PTS - 1);
    if (j < counts[b]) continue;
    *(float2*)(out + (size_t)m * O_DIM + lane * 2) = make_float2(0.f, 0.f);
    if (lane == 0) {
      float* oc = out + OUT_COORD_OFF;
      oc[m * 3] = 0.f; oc[m * 3 + 1] = 0.f; oc[m * 3 + 2] = 0.f;
      out[OUT_MASK_OFF + m] = 1.f;
    }
  }
}

extern "C" void kernel_launch(void* const* d_in, const int* in_sizes, int n_in,
                              void* d_out, int out_size, void* d_ws, size_t ws_size,
                              hipStream_t stream) {
  const float* pf = (const float*)d_in[0];
  const float* pc = (const float*)d_in[1];
  const float* w1 = (const float*)d_in[2];
  const float* b1 = (const float*)d_in[3];
  const float* w2 = (const float*)d_in[4];
  const float* b2 = (const float*)d_in[5];
  const float* wo = (const float*)d_in[6];
  const float* bo = (const float*)d_in[7];
  float* out = (float*)d_out;
  char* ws = (char*)d_ws;

  unsigned int* Wu = (unsigned int*)(ws + WT_OFF);
  unsigned long long* tmask = (unsigned long long*)(ws + TMASK_OFF);
  int* tagg = (int*)(ws + TAGG_OFF);
  int* texcl = (int*)(ws + TEXCL_OFF);
  int* counts = (int*)(ws + COUNTS_OFF);
  float* G = (float*)(ws + G_OFF);

  convert_w<<<240, 256, 0, stream>>>(w1, wo, Wu);
  gemm_fused<<<NBLOCKS, 768, 0, stream>>>(pf, (const unsigned char*)Wu, w1, b1,
                                          w2, b2, bo, tmask, tagg, G);
  scan_tiles<<<8, 256, 0, stream>>>(tagg, texcl, counts);
  scatter<<<NCHUNKS, 512, 0, stream>>>(G, tmask, texcl, pc, out);
  fill_tail<<<2048, 256, 0, stream>>>(counts, out);
}